// Round 12
// baseline (82.431 us; speedup 1.0000x reference)
//
#include <hip/hip_runtime.h>

// Batched 14-qubit statevector simulator, v9.
// v8 -> v9: fold readout into the final gate pass. Pass 5's state is only
// consumed by <Z_w>; the sign (-1)^parity(y & frow) splits into a constexpr
// per-slot part (t_w over lut bits -> 16-pt WHT) and a per-thread part
// (parity(repf & frow)). So pass 5 now ends with |e|^2 + in-register WHT +
// signed accumulate: the final state write (32 b64), the readout barrier,
// and the readout re-read (32 b64) are deleted - one full phase removed.
// Everything else identical to v8 (bank-spread wsel, VOP3P packed butterflies).

#define NQ 14
#define NS (1 << NQ)
#define NT 512
#define NTB 9                  // log2(NT)
#define NW (NT / 64)
#define NLAYERS 3

typedef float c2 __attribute__((ext_vector_type(2)));

// ---------------- compile-time GF(2) schedule ----------------
struct Sched {
    unsigned m2[NQ], r2[NQ];
    unsigned m3[NQ], r3[NQ];
    unsigned frow[NQ];
};

constexpr Sched make_sched() {
    Sched s{};
    unsigned c[NQ] = {}, r[NQ] = {};
    for (int w = 0; w < NQ; ++w) { c[w] = 1u << (NQ - 1 - w); r[w] = 1u << (NQ - 1 - w); }
    for (int ring = 0; ring < 3; ++ring) {
        for (int w = 0; w < NQ - 1; ++w) { c[w] ^= c[w + 1]; r[w + 1] ^= r[w]; }
        c[NQ - 1] ^= c[0]; r[0] ^= r[NQ - 1];
        if (ring == 0) for (int w = 0; w < NQ; ++w) { s.m2[w] = c[w]; s.r2[w] = r[w]; }
        if (ring == 1) for (int w = 0; w < NQ; ++w) { s.m3[w] = c[w]; s.r3[w] = r[w]; }
        if (ring == 2) for (int w = 0; w < NQ; ++w) { s.frow[w] = r[w]; }
    }
    return s;
}
constexpr Sched S = make_sched();

struct Meta {
    unsigned mask[5];
    unsigned row[5];
    unsigned lut[32];
    unsigned npiv;
    unsigned run_mask[NTB];
    int      run_shl[NTB];
    int      nruns;
    unsigned wsel[6];        // per-lane-bit in-coset offset (bank spread)
    int      posC;
    unsigned selhiC;
    int K;
    int g0;
};

constexpr Meta mkpass(const unsigned* m, const unsigned* r, int w0, int K, int g0base) {
    Meta p{};
    p.K = K; p.g0 = g0base + w0;
    for (int i = 0; i < K; ++i) { p.mask[i] = m[w0 + i]; p.row[i] = r[w0 + i]; }
    unsigned red[5] = {}, pivbit[5] = {}, pivs = 0;
    for (int i = 0; i < K; ++i) {
        unsigned v = p.mask[i];
        for (int j = 0; j < i; ++j) if (v & pivbit[j]) v ^= red[j];
        unsigned hb = 0;
        for (int b = 13; b >= 0; --b) if ((v >> b) & 1u) { hb = 1u << b; break; }
        red[i] = v; pivbit[i] = hb; pivs |= hb;
    }
    p.npiv = (~pivs) & 0x3FFFu;
    for (int j = 0; j < (1 << K); ++j) {
        unsigned x = 0;
        for (int i = 0; i < K; ++i) if ((j >> i) & 1) x ^= p.mask[i];
        p.lut[j] = x;
    }
    int pos[14] = {}; int nb = 0;
    for (int b = 0; b < 14; ++b) if ((p.npiv >> b) & 1) pos[nb++] = b;
    p.nruns = 0;
    int k = 0;
    while (k < NTB) {
        const int off = pos[k] - k;
        unsigned mm = 0;
        while (k < NTB && pos[k] - k == off) { mm |= 1u << k; ++k; }
        p.run_mask[p.nruns] = mm;
        p.run_shl[p.nruns] = off;
        ++p.nruns;
    }
    p.posC = (nb > NTB) ? pos[NTB] : 0;
    p.selhiC = 0;
    if (nb > NTB)
        for (int i = 0; i < K; ++i)
            p.selhiC |= ((p.row[i] >> p.posC) & 1u) << i;
    // bank-spread: wsel[i] in span{masks} so lane->(idx mod 16) reaches rank 4
    {
        unsigned basis[4] = {}; int nb2 = 0;
        for (int i = 0; i < 6; ++i) {
            p.wsel[i] = 0;
            bool done = false;
            for (int j = 0; j < (1 << K) && !done; ++j) {
                unsigned v = ((1u << pos[i]) ^ p.lut[j]) & 15u;
                for (int b = 0; b < nb2; ++b) {
                    unsigned hb = 0;
                    for (int t = 3; t >= 0; --t) if ((basis[b] >> t) & 1u) { hb = 1u << t; break; }
                    if (v & hb) v ^= basis[b];
                }
                if (v != 0) { basis[nb2++] = v; p.wsel[i] = p.lut[j]; done = true; }
            }
            if (nb2 == 4) break;
        }
    }
    return p;
}

constexpr Meta PM[6] = {
    mkpass(S.m2, S.r2, 0, 5, 0),  mkpass(S.m2, S.r2, 5, 5, 0),  mkpass(S.m2, S.r2, 10, 4, 0),
    mkpass(S.m3, S.r3, 0, 5, 14), mkpass(S.m3, S.r3, 5, 5, 14), mkpass(S.m3, S.r3, 10, 4, 14),
};
static_assert(__builtin_popcount(PM[0].npiv) == 9,  "GE failed p0");
static_assert(__builtin_popcount(PM[2].npiv) == 10, "GE failed p2");
static_assert(__builtin_popcount(PM[5].npiv) == 10, "GE failed p5");

// per-wire WHT bucket for the folded readout (pass 5, K=4):
// t_w bit i = parity(mask[i] & frow[w])
struct TWs { unsigned t[NQ]; };
constexpr TWs make_tws() {
    TWs r{};
    for (int w = 0; w < NQ; ++w) {
        unsigned t = 0;
        for (int i = 0; i < PM[5].K; ++i)
            t |= (unsigned)(__builtin_popcount(PM[5].mask[i] & S.frow[w]) & 1) << i;
        r.t[w] = t;
    }
    return r;
}
constexpr TWs TW = make_tws();

// ---------------- complex helpers (setup only) ----------------
struct c32 { float x, y; };
__device__ __forceinline__ c32 cmul(c32 a, c32 b) {
    return c32{ a.x * b.x - a.y * b.y, a.x * b.y + a.y * b.x };
}
__device__ __forceinline__ c32 cadd(c32 a, c32 b) { return c32{ a.x + b.x, a.y + b.y }; }
__device__ __forceinline__ c2 cmulv(c2 a, c2 b) {
    return (c2){ a.x * b.x - a.y * b.y, a.x * b.y + a.y * b.x };
}

struct M2x2 { c32 a, b, c, d; };
__device__ __forceinline__ M2x2 mmul(M2x2 X, M2x2 Y) {
    M2x2 o;
    o.a = cadd(cmul(X.a, Y.a), cmul(X.b, Y.c));
    o.b = cadd(cmul(X.a, Y.b), cmul(X.b, Y.d));
    o.c = cadd(cmul(X.c, Y.a), cmul(X.d, Y.c));
    o.d = cadd(cmul(X.c, Y.b), cmul(X.d, Y.d));
    return o;
}
__device__ __forceinline__ M2x2 mRX(float c, float s) { return M2x2{ {c,0.f},{0.f,-s},{0.f,-s},{c,0.f} }; }
__device__ __forceinline__ M2x2 mRY(float c, float s) { return M2x2{ {c,0.f},{-s,0.f},{s,0.f},{c,0.f} }; }
__device__ __forceinline__ M2x2 mRZ(float c, float s) { return M2x2{ {c,-s},{0.f,0.f},{0.f,0.f},{c,s} }; }

// ---------------- packed-FP32 primitives (VOP3P) ----------------
__device__ __forceinline__ c2 pk_mul(c2 a, c2 b) {
    c2 d; asm("v_pk_mul_f32 %0, %1, %2" : "=v"(d) : "v"(a), "v"(b)); return d;
}
__device__ __forceinline__ c2 pk_fma(c2 a, c2 b, c2 c) {
    c2 d; asm("v_pk_fma_f32 %0, %1, %2, %3" : "=v"(d) : "v"(a), "v"(b), "v"(c)); return d;
}
__device__ __forceinline__ c2 pk_fma_s(c2 a, c2 b, c2 c) {
    c2 d; asm("v_pk_fma_f32 %0, %1, %2, %3 op_sel:[1,0,0] op_sel_hi:[0,1,1]"
               : "=v"(d) : "v"(a), "v"(b), "v"(c)); return d;
}

// butterfly on (x, y) with broadcast-pair coeffs mp[0..7]
#define BFLY(x, y, mp, o0, o1)                      \
    {                                                \
        c2 _a0 = pk_mul(x, (mp)[0]);                 \
        _a0 = pk_fma_s(x, (mp)[1], _a0);             \
        _a0 = pk_fma(y, (mp)[2], _a0);               \
        _a0 = pk_fma_s(y, (mp)[3], _a0);             \
        c2 _a1 = pk_mul(x, (mp)[4]);                 \
        _a1 = pk_fma_s(x, (mp)[5], _a1);             \
        _a1 = pk_fma(y, (mp)[6], _a1);               \
        _a1 = pk_fma_s(y, (mp)[7], _a1);             \
        o0 = _a0; o1 = _a1;                          \
    }

// hoisted per-pass index math
template<int P>
__device__ __forceinline__ void pass_base(int tid, unsigned& base, unsigned& selb) {
    constexpr Meta pm = PM[P];
    unsigned rep = 0;
    #pragma unroll
    for (int rn = 0; rn < pm.nruns; ++rn)
        rep |= ((unsigned)tid & pm.run_mask[rn]) << pm.run_shl[rn];
    unsigned corr = 0;
    #pragma unroll
    for (int i = 0; i < 6; ++i)
        if (pm.wsel[i]) corr ^= ((tid >> i) & 1u) ? pm.wsel[i] : 0u;
    base = rep ^ corr;
    selb = 0;
    #pragma unroll
    for (int i = 0; i < PM[P].K; ++i)
        selb |= (unsigned)(__popc(base & pm.row[i]) & 1) << i;
}

// ---------------- grouped gate pass (state -> state) ----------------
template<int P>
__device__ __forceinline__ void do_pass(c2* st, const c2 (*gm)[2][8], int tid) {
    constexpr Meta pm = PM[P];
    constexpr int K = pm.K;
    constexpr int NSLOT = 1 << K;
    constexpr int NCS = (K == 5) ? 1 : 2;

    unsigned base, selb;
    pass_base<P>(tid, base, selb);

    #pragma unroll 1
    for (int cs = 0; cs < NCS; ++cs) {
        const unsigned repf = cs ? (base ^ (1u << pm.posC)) : base;
        const unsigned sel  = cs ? (selb ^ pm.selhiC) : selb;

        c2 e[NSLOT];
        #pragma unroll
        for (int j = 0; j < NSLOT; ++j) e[j] = st[repf ^ pm.lut[j]];

        #pragma unroll
        for (int w = 0; w < K; ++w) {
            const c2* mp = gm[pm.g0 + w][(sel >> w) & 1u];
            #pragma unroll
            for (int t = 0; t < NSLOT / 2; ++t) {
                const int j  = ((t >> w) << (w + 1)) | (t & ((1 << w) - 1));
                const int j2 = j | (1 << w);
                BFLY(e[j], e[j2], mp, e[j], e[j2]);
            }
        }
        #pragma unroll
        for (int j = 0; j < NSLOT; ++j) st[repf ^ pm.lut[j]] = e[j];
    }
}

// ---------------- final pass: gates + folded readout (no state write) ----
__device__ __forceinline__ void do_pass5_readout(const c2* st, const c2 (*gm)[2][8],
                                                 int tid, float* ev) {
    constexpr Meta pm = PM[5];
    constexpr int K = pm.K;          // 4
    constexpr int NSLOT = 1 << K;    // 16

    unsigned base, selb;
    pass_base<5>(tid, base, selb);

    #pragma unroll 1
    for (int cs = 0; cs < 2; ++cs) {
        const unsigned repf = cs ? (base ^ (1u << pm.posC)) : base;
        const unsigned sel  = cs ? (selb ^ pm.selhiC) : selb;

        c2 e[NSLOT];
        #pragma unroll
        for (int j = 0; j < NSLOT; ++j) e[j] = st[repf ^ pm.lut[j]];

        #pragma unroll
        for (int w = 0; w < K; ++w) {
            const c2* mp = gm[pm.g0 + w][(sel >> w) & 1u];
            #pragma unroll
            for (int t = 0; t < NSLOT / 2; ++t) {
                const int j  = ((t >> w) << (w + 1)) | (t & ((1 << w) - 1));
                const int j2 = j | (1 << w);
                BFLY(e[j], e[j2], mp, e[j], e[j2]);
            }
        }

        // |amp|^2 and 16-point WHT over the slot index j
        float W[NSLOT];
        #pragma unroll
        for (int j = 0; j < NSLOT; ++j) W[j] = e[j].x * e[j].x + e[j].y * e[j].y;
        #pragma unroll
        for (int bb = 0; bb < K; ++bb) {
            #pragma unroll
            for (int t = 0; t < NSLOT / 2; ++t) {
                const int j  = ((t >> bb) << (bb + 1)) | (t & ((1 << bb) - 1));
                const int j2 = j | (1 << bb);
                const float u = W[j], v = W[j2];
                W[j] = u + v; W[j2] = u - v;
            }
        }
        // ev[w] += (-1)^parity(repf & frow_w) * W[t_w]
        #pragma unroll
        for (int w = 0; w < NQ; ++w) {
            const float val = W[TW.t[w]];
            ev[w] += (__popc(repf & S.frow[w]) & 1) ? -val : val;
        }
    }
}

__global__ __launch_bounds__(NT, 2)
void qsim_kernel(const float* __restrict__ z, const float* __restrict__ th,
                 float* __restrict__ out)
{
    extern __shared__ c2 st[];                // 16384 x 8 B state
    __shared__ c2    gm[28][2][8];            // broadcast-pair gate coeffs
    __shared__ c2    vtab[NQ][2];
    __shared__ float red[NW][NQ];

    const int bq  = blockIdx.x;
    const int tid = threadIdx.x;

    // ---- metadata: fused gate matrices + per-wire product vectors ----
    if (tid < 28) {
        const int rd = tid / 14, w = tid % 14, l = rd + 1;
        const float* tp = th + (l * NQ + w) * 3;
        float s0, c0, s1, c1, s2, c2_;
        __sincosf(0.5f * tp[0], &s0, &c0);
        __sincosf(0.5f * tp[1], &s1, &c1);
        __sincosf(0.5f * tp[2], &s2, &c2_);
        const M2x2 G = mmul(mRZ(c2_, s2), mmul(mRY(c1, s1), mRX(c0, s0)));
        const c32 V[2][4] = { { G.a, G.b, G.c, G.d }, { G.d, G.c, G.b, G.a } };
        #pragma unroll
        for (int v = 0; v < 2; ++v) {
            #pragma unroll
            for (int q = 0; q < 4; ++q) {
                gm[tid][v][2 * q]     = (c2){ V[v][q].x,  V[v][q].x };
                gm[tid][v][2 * q + 1] = (c2){ -V[v][q].y, V[v][q].y };
            }
        }
    } else if (tid >= 32 && tid < 32 + NQ) {
        const int w = tid - 32;
        const float zt = z[bq * NQ + w];
        float sz_, cz_; __sincosf(0.5f * zt, &sz_, &cz_);
        const c32 a0{ cz_ * cz_, -cz_ * sz_ }, b0{ sz_ * cz_, sz_ * sz_ };
        const float* tp = th + (0 * NQ + w) * 3;
        float s0, c0, s1, c1, s2, c2_;
        __sincosf(0.5f * tp[0], &s0, &c0);
        __sincosf(0.5f * tp[1], &s1, &c1);
        __sincosf(0.5f * tp[2], &s2, &c2_);
        const M2x2 G = mmul(mRZ(c2_, s2), mmul(mRY(c1, s1), mRX(c0, s0)));
        const c32 v0 = cadd(cmul(G.a, a0), cmul(G.b, b0));
        const c32 v1 = cadd(cmul(G.c, a0), cmul(G.d, b0));
        vtab[w][0] = (c2){ v0.x, v0.y };
        vtab[w][1] = (c2){ v1.x, v1.y };
    }
    __syncthreads();

    // ---- init: product state (encoding + layer-1 folded) ----
    {
        c2 pf = vtab[13][tid & 1];
        #pragma unroll
        for (int p = 1; p < 9; ++p) pf = cmulv(pf, vtab[13 - p][(tid >> p) & 1]);
        #pragma unroll 1
        for (int cs = 0; cs < 2; ++cs) {
            c2 e16[16];
            e16[0] = cmulv(pf, vtab[0][cs]);
            #pragma unroll
            for (int bb = 0; bb < 4; ++bb) {
                const c2 v0 = vtab[4 - bb][0], v1 = vtab[4 - bb][1];
                #pragma unroll
                for (int t = 0; t < (1 << bb); ++t) {
                    const c2 base = e16[t];
                    e16[t + (1 << bb)] = cmulv(base, v1);
                    e16[t] = cmulv(base, v0);
                }
            }
            #pragma unroll
            for (int t = 0; t < 16; ++t) st[tid + ((cs * 16 + t) << 9)] = e16[t];
        }
    }
    __syncthreads();

    // ---- 5 state passes + final pass with folded readout ----
    do_pass<0>(st, gm, tid); __syncthreads();
    do_pass<1>(st, gm, tid); __syncthreads();
    do_pass<2>(st, gm, tid); __syncthreads();
    do_pass<3>(st, gm, tid); __syncthreads();
    do_pass<4>(st, gm, tid); __syncthreads();

    float ev[NQ];
    #pragma unroll
    for (int w = 0; w < NQ; ++w) ev[w] = 0.f;
    do_pass5_readout(st, gm, tid, ev);

    // ---- cross-thread reduction ----
    const int lane = tid & 63, wv = tid >> 6;
    #pragma unroll
    for (int w = 0; w < NQ; ++w) {
        float v = ev[w];
        #pragma unroll
        for (int off = 32; off > 0; off >>= 1) v += __shfl_down(v, off, 64);
        if (lane == 0) red[wv][w] = v;
    }
    __syncthreads();
    if (tid < NQ) {
        float v = 0.f;
        #pragma unroll
        for (int i = 0; i < NW; ++i) v += red[i][tid];
        out[bq * NQ + tid] = v;
    }
}

extern "C" void kernel_launch(void* const* d_in, const int* in_sizes, int n_in,
                              void* d_out, int out_size, void* d_ws, size_t ws_size,
                              hipStream_t stream)
{
    (void)n_in; (void)out_size; (void)d_ws; (void)ws_size;
    const float* z  = (const float*)d_in[0];   // (256, 14) float32
    const float* th = (const float*)d_in[1];   // (3, 14, 3) float32
    float* out = (float*)d_out;                // (256, 14) float32

    const int B = in_sizes[0] / NQ;

    hipFuncSetAttribute(reinterpret_cast<const void*>(qsim_kernel),
                        hipFuncAttributeMaxDynamicSharedMemorySize, NS * 8);

    qsim_kernel<<<dim3(B), dim3(NT), NS * 8, stream>>>(z, th, out);
}